// Round 4
// baseline (57.044 us; speedup 1.0000x reference)
//
#include <hip/hip_runtime.h>

#define TT 1024
#define NN 1024
#define TS (TT - 1)   // 1023 rows of actual computation
#define RPB 8         // t-rows per block
#define BT 512        // threads per block (8 waves)

typedef float v4f __attribute__((ext_vector_type(4)));

__global__ __launch_bounds__(BT) void fused_traj_kernel(
    const float* __restrict__ a,
    const float* __restrict__ W1, const float* __restrict__ b1,
    const float* __restrict__ W2, const float* __restrict__ b2,
    const float* __restrict__ W3, const float* __restrict__ b3,
    const float* __restrict__ W4, const float* __restrict__ b4,
    const float* __restrict__ W5, const float* __restrict__ b5,
    const float* __restrict__ W6, const float* __restrict__ b6,
    float* __restrict__ out1, float* __restrict__ out64)
{
    __shared__ float sFeat[RPB][64 * 4];   // feat[row][agent][4]  (8 KB)

    const int bid    = blockIdx.x;
    const int tchunk = bid >> 4;           // 0..127
    const int n0     = (bid & 15) << 6;    // 0,64,...,960
    const int tid    = threadIdx.x;
    const int ts0    = tchunk * RPB;       // 0..1016
    const int rows   = min(RPB, TS - ts0); // 8 (7 for last chunk)

    // ---- Phase 1: wave r computes row ts0+r (8 waves, 1 row each) ----
    const int wv   = tid >> 6;   // 0..7
    const int lane = tid & 63;

    if (wv < rows) {
        const int ts = ts0 + wv;
        const int n  = n0 + lane;
        const float2* a2 = (const float2*)a;
        const float2 p   = a2[(size_t)(ts + 1) * NN + n];
        const float2 pr  = a2[(size_t)ts * NN + n];
        const float2 pj  = a2[(size_t)(ts + 1) * NN + (NN - 1)];
        const float2 prj = a2[(size_t)ts * NN + (NN - 1)];

        const float dx  = p.x - pj.x, dy = p.y - pj.y;
        const float dis = sqrtf(dx * dx + dy * dy);

        const float ddx = p.x - pr.x, ddy = p.y - pr.y;
        const float v   = sqrtf(ddx * ddx + ddy * ddy) * 2.0f;  // / DT
        const float ang = atan2f(ddy, ddx);

        const float jdx = pj.x - prj.x, jdy = pj.y - prj.y;
        const float vj   = sqrtf(jdx * jdx + jdy * jdy) * 2.0f;
        const float angj = atan2f(jdy, jdx);

        const float mask = (dis <= 12.0f) ? 1.0f : 0.0f;

        const float x_m = W1[0] * p.x + W1[1] * (mask * pj.x) + b1[0];
        const float y_m = W2[0] * p.y + W2[1] * (mask * pj.y) + b2[0];
        const float v_m = W3[0] * v   + W3[1] * (mask * vj)   + b3[0];
        const float a_m = W4[0] * ang + W4[1] * (mask * angj) + b4[0];

        const float sss = W5[0] * x_m + W5[1] * y_m + W5[2] * v_m +
                          W5[3] * a_m + b5[0];

        __builtin_nontemporal_store(sss, &out1[(size_t)(ts + 1) * NN + n]);
        if (tchunk == 0 && wv == 0)
            __builtin_nontemporal_store(sss, &out1[n]);   // duplicated row 0

        sFeat[wv][lane * 4 + 0] = x_m;
        sFeat[wv][lane * 4 + 1] = y_m;
        sFeat[wv][lane * 4 + 2] = v_m;
        sFeat[wv][lane * 4 + 3] = a_m;
    }

    // ---- This thread's 4 fixed W6 channels in registers ----
    const int c0 = (tid & 15) * 4;         // fixed channel quad
    float4 w6r[4];
    float  b6r[4];
#pragma unroll
    for (int k = 0; k < 4; ++k) {
        w6r[k] = ((const float4*)W6)[c0 + k];   // row (c0+k) of W6 (64x4)
        b6r[k] = b6[c0 + k];
    }

    __syncthreads();

    // ---- Phase 2: coalesced out64 writes ----
    // flat float4 index g = tid + BT*it over the 8x64x64 tile (8192 float4)
    // row = it>>1, agent = (tid>>4) + 32*(it&1), channels c0..c0+3
    const int ahalf = tid >> 4;            // 0..31
    float* base = out64 + ((size_t)(ts0 + 1) * NN + n0) * 64;

#pragma unroll
    for (int it = 0; it < 16; ++it) {
        const int r = it >> 1;
        if (r >= rows) break;
        const int agent = ahalf + 32 * (it & 1);
        const float4 ft = ((const float4*)sFeat[r])[agent];  // 16-lane bcast

        v4f o;
        o.x = ft.x * w6r[0].x + ft.y * w6r[0].y + ft.z * w6r[0].z + ft.w * w6r[0].w + b6r[0];
        o.y = ft.x * w6r[1].x + ft.y * w6r[1].y + ft.z * w6r[1].z + ft.w * w6r[1].w + b6r[1];
        o.z = ft.x * w6r[2].x + ft.y * w6r[2].y + ft.z * w6r[2].z + ft.w * w6r[2].w + b6r[2];
        o.w = ft.x * w6r[3].x + ft.y * w6r[3].y + ft.z * w6r[3].z + ft.w * w6r[3].w + b6r[3];

        const size_t f = (size_t)r * (NN * 64) + agent * 64 + c0;
        __builtin_nontemporal_store(o, (v4f*)(base + f));
        if (tchunk == 0 && r == 0)
            __builtin_nontemporal_store(o, (v4f*)(out64 + (size_t)n0 * 64 + agent * 64 + c0));
    }
}

extern "C" void kernel_launch(void* const* d_in, const int* in_sizes, int n_in,
                              void* d_out, int out_size, void* d_ws, size_t ws_size,
                              hipStream_t stream)
{
    const float* a  = (const float*)d_in[0];
    const float* W1 = (const float*)d_in[1];
    const float* b1 = (const float*)d_in[2];
    const float* W2 = (const float*)d_in[3];
    const float* b2 = (const float*)d_in[4];
    const float* W3 = (const float*)d_in[5];
    const float* b3 = (const float*)d_in[6];
    const float* W4 = (const float*)d_in[7];
    const float* b4 = (const float*)d_in[8];
    const float* W5 = (const float*)d_in[9];
    const float* b5 = (const float*)d_in[10];
    const float* W6 = (const float*)d_in[11];
    const float* b6 = (const float*)d_in[12];

    float* out1  = (float*)d_out;                    // 1024*1024 floats
    float* out64 = out1 + (size_t)TT * NN;           // 1024*1024*64 floats

    const int chunks = (TS + RPB - 1) / RPB;         // 128
    const int grid   = chunks * (NN / 64);           // 2048
    fused_traj_kernel<<<grid, BT, 0, stream>>>(
        a, W1, b1, W2, b2, W3, b3, W4, b4, W5, b5, W6, b6, out1, out64);
}

// Round 5
// 55.452 us; speedup vs baseline: 1.0287x; 1.0287x over previous
//
#include <hip/hip_runtime.h>

#define TT 1024
#define NN 1024
#define BT 256        // threads per block (4 waves)

typedef float v4f __attribute__((ext_vector_type(4)));

// Block b writes out1 row b (4 KB) and out64 row b (256 KB), both contiguous.
// Row b of the outputs = sss row rb, rb = (b==0) ? 0 : b-1.
__global__ __launch_bounds__(BT) void fused_traj_kernel(
    const float* __restrict__ a,
    const float* __restrict__ W1, const float* __restrict__ b1,
    const float* __restrict__ W2, const float* __restrict__ b2,
    const float* __restrict__ W3, const float* __restrict__ b3,
    const float* __restrict__ W4, const float* __restrict__ b4,
    const float* __restrict__ W5, const float* __restrict__ b5,
    const float* __restrict__ W6, const float* __restrict__ b6,
    float* __restrict__ out1, float* __restrict__ out64)
{
    __shared__ float sFeat[NN * 4];        // feat[agent][4]  (16 KB)

    const int b   = blockIdx.x;            // 0..1023
    const int rb  = (b == 0) ? 0 : b - 1;  // sss row this block materializes
    const int tid = threadIdx.x;

    const float2* a2 = (const float2*)a;

    // ---- joint-agent quantities (uniform across block) ----
    const float2 pj  = a2[(size_t)(rb + 1) * NN + (NN - 1)];
    const float2 prj = a2[(size_t)rb * NN + (NN - 1)];
    const float jdx = pj.x - prj.x, jdy = pj.y - prj.y;
    const float vj   = sqrtf(jdx * jdx + jdy * jdy) * 2.0f;   // / DT
    const float angj = atan2f(jdy, jdx);

    // ---- Phase 1: each thread computes 4 agents (coalesced) ----
#pragma unroll
    for (int k = 0; k < 4; ++k) {
        const int n = tid + BT * k;        // 0..1023, lane-consecutive
        const float2 p  = a2[(size_t)(rb + 1) * NN + n];
        const float2 pr = a2[(size_t)rb * NN + n];

        const float dx  = p.x - pj.x, dy = p.y - pj.y;
        const float dis = sqrtf(dx * dx + dy * dy);

        const float ddx = p.x - pr.x, ddy = p.y - pr.y;
        const float v   = sqrtf(ddx * ddx + ddy * ddy) * 2.0f;
        const float ang = atan2f(ddy, ddx);

        const float mask = (dis <= 12.0f) ? 1.0f : 0.0f;

        const float x_m = W1[0] * p.x + W1[1] * (mask * pj.x) + b1[0];
        const float y_m = W2[0] * p.y + W2[1] * (mask * pj.y) + b2[0];
        const float v_m = W3[0] * v   + W3[1] * (mask * vj)   + b3[0];
        const float a_m = W4[0] * ang + W4[1] * (mask * angj) + b4[0];

        const float sss = W5[0] * x_m + W5[1] * y_m + W5[2] * v_m +
                          W5[3] * a_m + b5[0];

        __builtin_nontemporal_store(sss, &out1[(size_t)b * NN + n]);

        sFeat[n * 4 + 0] = x_m;
        sFeat[n * 4 + 1] = y_m;
        sFeat[n * 4 + 2] = v_m;
        sFeat[n * 4 + 3] = a_m;
    }

    // ---- This thread's 4 fixed W6 channels in registers ----
    const int c0 = (tid & 15) * 4;         // fixed channel quad
    float4 w6r[4];
    float  b6r[4];
#pragma unroll
    for (int k = 0; k < 4; ++k) {
        w6r[k] = ((const float4*)W6)[c0 + k];
        b6r[k] = b6[c0 + k];
    }

    __syncthreads();

    // ---- Phase 2: 256 KB contiguous nt stores, ascending ----
    // flat float4 index g = tid + BT*it;  agent = g>>4, chan quad = (g&15)*4
    float* dst = out64 + (size_t)b * (NN * 64) + tid * 4;
    const int a0 = tid >> 4;               // 0..15, +16 per it

#pragma unroll 8
    for (int it = 0; it < 64; ++it) {
        const float4 ft = ((const float4*)sFeat)[a0 + 16 * it]; // 16-lane bcast

        v4f o;
        o.x = ft.x * w6r[0].x + ft.y * w6r[0].y + ft.z * w6r[0].z + ft.w * w6r[0].w + b6r[0];
        o.y = ft.x * w6r[1].x + ft.y * w6r[1].y + ft.z * w6r[1].z + ft.w * w6r[1].w + b6r[1];
        o.z = ft.x * w6r[2].x + ft.y * w6r[2].y + ft.z * w6r[2].z + ft.w * w6r[2].w + b6r[2];
        o.w = ft.x * w6r[3].x + ft.y * w6r[3].y + ft.z * w6r[3].z + ft.w * w6r[3].w + b6r[3];

        __builtin_nontemporal_store(o, (v4f*)(dst + (size_t)it * (BT * 4)));
    }
}

extern "C" void kernel_launch(void* const* d_in, const int* in_sizes, int n_in,
                              void* d_out, int out_size, void* d_ws, size_t ws_size,
                              hipStream_t stream)
{
    const float* a  = (const float*)d_in[0];
    const float* W1 = (const float*)d_in[1];
    const float* b1 = (const float*)d_in[2];
    const float* W2 = (const float*)d_in[3];
    const float* b2 = (const float*)d_in[4];
    const float* W3 = (const float*)d_in[5];
    const float* b3 = (const float*)d_in[6];
    const float* W4 = (const float*)d_in[7];
    const float* b4 = (const float*)d_in[8];
    const float* W5 = (const float*)d_in[9];
    const float* b5 = (const float*)d_in[10];
    const float* W6 = (const float*)d_in[11];
    const float* b6 = (const float*)d_in[12];

    float* out1  = (float*)d_out;                    // 1024*1024 floats
    float* out64 = out1 + (size_t)TT * NN;           // 1024*1024*64 floats

    fused_traj_kernel<<<TT, BT, 0, stream>>>(
        a, W1, b1, W2, b2, W3, b3, W4, b4, W5, b5, W6, b6, out1, out64);
}